// Round 5
// baseline (939.608 us; speedup 1.0000x reference)
//
#include <hip/hip_runtime.h>
#include <hip/hip_bf16.h>
#include <math.h>

#define B 64
#define S 64
#define T 21
#define ENC_D 512
#define HID 512
#define VOCAB 32000

typedef __bf16 bf16x8 __attribute__((ext_vector_type(8)));
typedef float f32x4 __attribute__((ext_vector_type(4)));

union BF8 { unsigned short u[8]; bf16x8 v; uint4 q; };

__device__ __forceinline__ unsigned short f32_to_bf16_rne(float x) {
    union { float f; unsigned int u; } v;
    v.f = x;
    unsigned int u = v.u;
    unsigned int r = (u + 0x7FFFu + ((u >> 16) & 1u)) >> 16;
    return (unsigned short)r;
}

__device__ __forceinline__ float bf16_to_f32(unsigned short x) {
    union { unsigned int u; float f; } v;
    v.u = ((unsigned int)x) << 16;
    return v.f;
}

__device__ __forceinline__ bf16x8 cvt8(const float* p) {
    float4 f0 = *(const float4*)p;
    float4 f1 = *(const float4*)(p + 4);
    BF8 r;
    r.u[0] = f32_to_bf16_rne(f0.x); r.u[1] = f32_to_bf16_rne(f0.y);
    r.u[2] = f32_to_bf16_rne(f0.z); r.u[3] = f32_to_bf16_rne(f0.w);
    r.u[4] = f32_to_bf16_rne(f1.x); r.u[5] = f32_to_bf16_rne(f1.y);
    r.u[6] = f32_to_bf16_rne(f1.z); r.u[7] = f32_to_bf16_rne(f1.w);
    return r.v;
}

// ---------------------------------------------------------------------------
// Fused setup: block ranges
//   [0,64)        h0: concat(enc_h, style[:,3]) @ W_e2d.T + b -> hbf0 ; c=0
//   [64,2112)     wcconv: [w_ih|w_hh] -> bf16 wcbf (one n row per block)
//   [2112,3136)   encconv: enc_out fp32 -> bf16
//   [3136,3472)   ebf: emb_table[dec_in] -> bf16, all (b,t)
//   [3472,3984)   mgemm: M[bs][j] = enc . attn_W (bf16 out), inline cvt
// ---------------------------------------------------------------------------
__global__ __launch_bounds__(256) void setup_kernel(
        const float* __restrict__ enc_h, const float* __restrict__ style,
        const float* __restrict__ W_e2d, const float* __restrict__ W_e2d_b,
        const float* __restrict__ enc_out, const float* __restrict__ attn_W,
        const float* __restrict__ w_ih, const float* __restrict__ w_hh,
        const float* __restrict__ emb_table, const int* __restrict__ dec_in,
        unsigned short* __restrict__ hbf0, float* __restrict__ c,
        unsigned short* __restrict__ wcbf, unsigned short* __restrict__ encbf,
        unsigned short* __restrict__ ebf, unsigned short* __restrict__ M_bf) {
    int bid = blockIdx.x;
    int tid = threadIdx.x;
    __shared__ __attribute__((aligned(16))) float smem[640];

    if (bid < 64) {
        int b = bid;
        for (int i = tid; i < 512; i += 256) smem[i] = enc_h[b * 512 + i];
        if (tid < 128) smem[512 + tid] = style[b * 512 + 384 + tid];
        __syncthreads();
        for (int j = tid; j < 512; j += 256) {
            const float4* w4 = (const float4*)(W_e2d + (size_t)j * 640);
            float acc = 0.f;
#pragma unroll 4
            for (int k4 = 0; k4 < 160; k4++) {
                float4 w = w4[k4];
                float4 iv = *(const float4*)(smem + k4 * 4);
                acc += w.x * iv.x + w.y * iv.y + w.z * iv.z + w.w * iv.w;
            }
            hbf0[b * 512 + j] = f32_to_bf16_rne(acc + W_e2d_b[j]);
            c[j * 64 + b] = 0.f;
        }
    } else if (bid < 2112) {
        int n = bid - 64;
        for (int k = tid; k < 1536; k += 256) {
            float v = (k < 1024) ? w_ih[(size_t)n * 1024 + k]
                                 : w_hh[(size_t)n * 512 + (k - 1024)];
            wcbf[(size_t)n * 1536 + k] = f32_to_bf16_rne(v);
        }
    } else if (bid < 3136) {
        size_t i = ((size_t)(bid - 2112) * 256 + tid) * 8;
        BF8 p; p.v = cvt8(enc_out + i);
        *(uint4*)(encbf + i) = p.q;
    } else if (bid < 3472) {
        size_t lin = ((size_t)(bid - 3136) * 256 + tid) * 8;
        int bt = (int)(lin >> 9);
        int off = (int)(lin & 511);
        int token = dec_in[bt];
        BF8 p; p.v = cvt8(emb_table + (size_t)token * 512 + off);
        *(uint4*)(ebf + lin) = p.q;
    } else {
        int idx = bid - 3472;
        int xm = idx & 63, y = idx >> 6;
        int w = tid >> 6, lane = tid & 63;
        int col = lane & 15, kq = lane >> 4;
        int m0 = xm * 64 + w * 16;

        bf16x8 af[16];
        const float* arow = enc_out + (size_t)(m0 + col) * 512 + kq * 8;
#pragma unroll
        for (int ks = 0; ks < 16; ks++) af[ks] = cvt8(arow + ks * 32);

#pragma unroll
        for (int nt = 0; nt < 4; nt++) {
            int j0 = y * 64 + nt * 16;
            const float* brow = attn_W + (size_t)(j0 + col) * 512 + kq * 8;
            f32x4 acc = {0.f, 0.f, 0.f, 0.f};
#pragma unroll
            for (int ks = 0; ks < 16; ks++) {
                bf16x8 bf = cvt8(brow + ks * 32);
                acc = __builtin_amdgcn_mfma_f32_16x16x32_bf16(af[ks], bf, acc, 0, 0, 0);
            }
#pragma unroll
            for (int reg = 0; reg < 4; reg++) {
                int m = m0 + kq * 4 + reg;
                M_bf[(size_t)m * 512 + j0 + col] = f32_to_bf16_rne(acc[reg]);
            }
        }
    }
}

// ---------------------------------------------------------------------------
// K1 per step: scores[b][s] = M[b][s]·h[b]; softmax; ctx = attn @ enc.
// grid(64)=b, block(256). h staged in LDS; scores parallel over (s,q).
// ---------------------------------------------------------------------------
__global__ __launch_bounds__(256) void attn_step_kernel(
        const unsigned short* __restrict__ hbf_in,
        const unsigned short* __restrict__ M_bf,
        const unsigned short* __restrict__ encbf,
        unsigned short* __restrict__ xbf) {
    int b = blockIdx.x;
    int tid = threadIdx.x;
    int s = tid & 63, q = tid >> 6;

    __shared__ float hs[512];
    __shared__ float scp[4][64];
    __shared__ float sc[64];

    hs[tid] = bf16_to_f32(hbf_in[b * 512 + tid]);
    hs[tid + 256] = bf16_to_f32(hbf_in[b * 512 + tid + 256]);
    __syncthreads();

    // partial score over u in [q*128, q*128+128)
    {
        const unsigned short* mrow = M_bf + ((size_t)(b * 64 + s)) * 512 + q * 128;
        const float* hq = hs + q * 128;
        float acc = 0.f;
#pragma unroll
        for (int i = 0; i < 16; i++) {
            BF8 mp; mp.v = *reinterpret_cast<const bf16x8*>(mrow + i * 8);
#pragma unroll
            for (int j = 0; j < 8; j++)
                acc += bf16_to_f32(mp.u[j]) * hq[i * 8 + j];
        }
        scp[q][s] = acc;
    }
    __syncthreads();

    if (tid < 64) {
        float v = scp[0][tid] + scp[1][tid] + scp[2][tid] + scp[3][tid];
        float m = v;
        for (int off = 32; off > 0; off >>= 1) m = fmaxf(m, __shfl_xor(m, off, 64));
        float e = __expf(v - m);
        float ssum = e;
        for (int off = 32; off > 0; off >>= 1) ssum += __shfl_xor(ssum, off, 64);
        sc[tid] = e / ssum;
    }
    __syncthreads();

    {
        int d0 = tid, d1 = tid + 256;
        float a0 = 0.f, a1 = 0.f;
        const unsigned short* ep = encbf + (size_t)b * 64 * 512;
#pragma unroll 4
        for (int si = 0; si < 64; si++) {
            float a = sc[si];
            a0 += a * bf16_to_f32(ep[(size_t)si * 512 + d0]);
            a1 += a * bf16_to_f32(ep[(size_t)si * 512 + d1]);
        }
        xbf[b * 512 + d0] = f32_to_bf16_rne(a0);
        xbf[b * 512 + d1] = f32_to_bf16_rne(a1);
    }
}

// ---------------------------------------------------------------------------
// K2 per step: gates (16 gate rows x 64 b) via MFMA + LSTM update.
// grid(128), block(256). A = [ctx | emb | h] all bf16; B staged in LDS.
// ---------------------------------------------------------------------------
__global__ __launch_bounds__(256) void gates_step_kernel(
        const unsigned short* __restrict__ xbf,
        const unsigned short* __restrict__ hbf_in,
        unsigned short* __restrict__ hbf_out,
        const unsigned short* __restrict__ ebf,
        const unsigned short* __restrict__ wcbf,
        const float* __restrict__ b_ih, const float* __restrict__ b_hh,
        float* __restrict__ c, unsigned short* __restrict__ hseqb, int t) {
    int tid = threadIdx.x;
    int u0 = blockIdx.x * 4;
    int w = tid >> 6, lane = tid & 63;
    int col = lane & 15, kq = lane >> 4;

    __shared__ __attribute__((aligned(16))) unsigned short blds[16 * 1544];
    __shared__ float glds[64 * 17];

#pragma unroll
    for (int i = 0; i < 12; i++) {
        int idx = i * 256 + tid;
        int r = idx / 192, c8 = (idx % 192) * 8;
        int gr = (r >> 2) * 512 + u0 + (r & 3);
        *(uint4*)(blds + r * 1544 + c8) =
            *(const uint4*)(wcbf + (size_t)gr * 1536 + c8);
    }
    __syncthreads();

    int bA = w * 16 + col;
    const unsigned short* ctxrow = xbf + bA * 512 + kq * 8;
    const unsigned short* hrow = hbf_in + bA * 512 + kq * 8;
    const unsigned short* erow = ebf + ((size_t)bA * T + t) * 512 + kq * 8;
    const unsigned short* brow = blds + col * 1544 + kq * 8;

    f32x4 acc = {0.f, 0.f, 0.f, 0.f};
#pragma unroll
    for (int ks = 0; ks < 16; ks++) {
        bf16x8 af = *reinterpret_cast<const bf16x8*>(ctxrow + ks * 32);
        bf16x8 bf = *reinterpret_cast<const bf16x8*>(brow + ks * 32);
        acc = __builtin_amdgcn_mfma_f32_16x16x32_bf16(af, bf, acc, 0, 0, 0);
    }
#pragma unroll
    for (int ks = 0; ks < 16; ks++) {
        bf16x8 af = *reinterpret_cast<const bf16x8*>(erow + ks * 32);
        bf16x8 bf = *reinterpret_cast<const bf16x8*>(brow + (16 + ks) * 32);
        acc = __builtin_amdgcn_mfma_f32_16x16x32_bf16(af, bf, acc, 0, 0, 0);
    }
#pragma unroll
    for (int ks = 0; ks < 16; ks++) {
        bf16x8 af = *reinterpret_cast<const bf16x8*>(hrow + ks * 32);
        bf16x8 bf = *reinterpret_cast<const bf16x8*>(brow + (32 + ks) * 32);
        acc = __builtin_amdgcn_mfma_f32_16x16x32_bf16(af, bf, acc, 0, 0, 0);
    }

#pragma unroll
    for (int reg = 0; reg < 4; reg++) {
        glds[(w * 16 + kq * 4 + reg) * 17 + col] = acc[reg];
    }
    __syncthreads();

    {
        int b = tid & 63, u_l = tid >> 6;
        int u = u0 + u_l;
        float gi = glds[b * 17 + u_l]      + b_ih[u]        + b_hh[u];
        float gf = glds[b * 17 + 4 + u_l]  + b_ih[512 + u]  + b_hh[512 + u];
        float gg = glds[b * 17 + 8 + u_l]  + b_ih[1024 + u] + b_hh[1024 + u];
        float go = glds[b * 17 + 12 + u_l] + b_ih[1536 + u] + b_hh[1536 + u];
        float ig = 1.f / (1.f + __expf(-gi));
        float fg = 1.f / (1.f + __expf(-gf));
        float gt = tanhf(gg);
        float og = 1.f / (1.f + __expf(-go));
        float cn = fg * c[u * 64 + b] + ig * gt;
        float hn = og * tanhf(cn);
        c[u * 64 + b] = cn;
        unsigned short hb = f32_to_bf16_rne(hn);
        hbf_out[b * 512 + u] = hb;
        hseqb[((size_t)b * T + t) * 512 + u] = hb;
    }
}

// ---------------------------------------------------------------------------
// Projection + exp-sum, SWAPPED operands: arg0 = proj_w rows (n), arg1 = hseq
// rows (m). D.row = n (kq*4+reg), D.col = m (lane&15). Lane epilogue: 4 exps
// for one m -> one LDS atomicAdd. grid(500), block(256): wave w owns 16 n.
// ---------------------------------------------------------------------------
__global__ __launch_bounds__(256) void proj_mfma_kernel(
        const unsigned short* __restrict__ hseqb,
        const float* __restrict__ proj_w,
        const float* __restrict__ proj_b,
        float* __restrict__ partial) {
    int tid = threadIdx.x;
    int w = tid >> 6, lane = tid & 63;
    int col = lane & 15, kq = lane >> 4;
    int nrow = blockIdx.x * 64 + w * 16;

    // hoist A-frags (weights) with inline fp32->bf16
    bf16x8 Af[16];
    {
        const float* wrow = proj_w + (size_t)(nrow + col) * 512 + kq * 8;
#pragma unroll
        for (int ks = 0; ks < 16; ks++) Af[ks] = cvt8(wrow + ks * 32);
    }
    float4 bias4 = *(const float4*)(proj_b + nrow + kq * 4);

    __shared__ float esum[1344];
    for (int i = tid; i < 1344; i += 256) esum[i] = 0.f;
    __syncthreads();

    for (int mt = 0; mt < 42; mt++) {
        int mA = mt * 32;
        const unsigned short* b0 = hseqb + (size_t)(mA + col) * 512 + kq * 8;
        const unsigned short* b1 = b0 + 16 * 512;
        f32x4 acc0 = {0.f, 0.f, 0.f, 0.f};
        f32x4 acc1 = {0.f, 0.f, 0.f, 0.f};
#pragma unroll
        for (int ks = 0; ks < 16; ks++) {
            bf16x8 bf0 = *reinterpret_cast<const bf16x8*>(b0 + ks * 32);
            bf16x8 bf1 = *reinterpret_cast<const bf16x8*>(b1 + ks * 32);
            acc0 = __builtin_amdgcn_mfma_f32_16x16x32_bf16(Af[ks], bf0, acc0, 0, 0, 0);
            acc1 = __builtin_amdgcn_mfma_f32_16x16x32_bf16(Af[ks], bf1, acc1, 0, 0, 0);
        }
        float e0 = __expf(acc0[0] + bias4.x) + __expf(acc0[1] + bias4.y) +
                   __expf(acc0[2] + bias4.z) + __expf(acc0[3] + bias4.w);
        float e1 = __expf(acc1[0] + bias4.x) + __expf(acc1[1] + bias4.y) +
                   __expf(acc1[2] + bias4.z) + __expf(acc1[3] + bias4.w);
        atomicAdd(&esum[mA + col], e0);
        atomicAdd(&esum[mA + 16 + col], e1);
    }
    __syncthreads();
    for (int i = tid; i < 1344; i += 256)
        partial[(size_t)blockIdx.x * 1344 + i] = esum[i];
}

// ---------------------------------------------------------------------------
// Reduce partial[500][1344] -> sumexp. grid(42), block(256): 32 m/block,
// 8-thread split over the 500 blocks.
// ---------------------------------------------------------------------------
__global__ __launch_bounds__(256) void sumexp_reduce_kernel(
        const float* __restrict__ partial, float* __restrict__ sumexp) {
    int m = blockIdx.x * 32 + (threadIdx.x >> 3);
    int sub = threadIdx.x & 7;
    float s = 0.f;
    for (int nb = sub; nb < 500; nb += 8) s += partial[(size_t)nb * 1344 + m];
    s += __shfl_xor(s, 1, 64);
    s += __shfl_xor(s, 2, 64);
    s += __shfl_xor(s, 4, 64);
    if (sub == 0) sumexp[m] = s;
}

// ---------------------------------------------------------------------------
__global__ __launch_bounds__(64) void loss_kernel(
        const unsigned short* __restrict__ hseqb,
        const float* __restrict__ proj_w, const float* __restrict__ proj_b,
        const float* __restrict__ sumexp, const int* __restrict__ seq_label,
        float* __restrict__ out) {
    int b = blockIdx.x;
    int lane = threadIdx.x;
    float num = 0.f, den = 0.f;
    for (int t = 0; t < T; t++) {
        int label = seq_label[b * T + t];
        const unsigned short* hp = hseqb + ((size_t)b * T + t) * 512;
        const float* wp = proj_w + (size_t)label * 512;
        float acc = 0.f;
#pragma unroll
        for (int i = 0; i < 8; i++)
            acc += bf16_to_f32(hp[lane + 64 * i]) * wp[lane + 64 * i];
        for (int off = 32; off > 0; off >>= 1) acc += __shfl_xor(acc, off, 64);
        if (lane == 0) {
            float nll = logf(sumexp[b * T + t]) - (acc + proj_b[label]);
            float mask = (label > 0) ? 1.f : 0.f;
            num += mask * nll;
            den += mask;
        }
    }
    if (lane == 0) atomicAdd(out, (num / (den + 1e-6f)) * (1.f / 64.f));
}

// ---------------------------------------------------------------------------
extern "C" void kernel_launch(void* const* d_in, const int* in_sizes, int n_in,
                              void* d_out, int out_size, void* d_ws, size_t ws_size,
                              hipStream_t stream) {
    const float* enc_h     = (const float*)d_in[0];
    const float* enc_out   = (const float*)d_in[1];
    const int*   seq_label = (const int*)d_in[3];
    const int*   dec_in    = (const int*)d_in[4];
    const float* style     = (const float*)d_in[5];
    const float* W_e2d_w   = (const float*)d_in[6];
    const float* W_e2d_b   = (const float*)d_in[7];
    const float* attn_W    = (const float*)d_in[8];
    const float* emb_table = (const float*)d_in[9];
    const float* w_ih      = (const float*)d_in[10];
    const float* w_hh      = (const float*)d_in[11];
    const float* b_ih      = (const float*)d_in[12];
    const float* b_hh      = (const float*)d_in[13];
    const float* proj_w    = (const float*)d_in[14];
    const float* proj_b    = (const float*)d_in[15];
    float* out = (float*)d_out;

    char* p = (char*)d_ws;
    float* c        = (float*)p;            p += 512 * 64 * 4;
    float* partial  = (float*)p;            p += 500 * 1344 * 4;
    float* sumexp   = (float*)p;            p += 1344 * 4 + 64;
    unsigned short* M_bf  = (unsigned short*)p; p += 4096 * 512 * 2;
    unsigned short* encbf = (unsigned short*)p; p += 4096 * 512 * 2;
    unsigned short* wcbf  = (unsigned short*)p; p += 2048 * 1536 * 2;
    unsigned short* ebf   = (unsigned short*)p; p += 1344 * 512 * 2;
    unsigned short* hseqb = (unsigned short*)p; p += 1344 * 512 * 2;
    unsigned short* hbuf0 = (unsigned short*)p; p += 64 * 512 * 2;
    unsigned short* hbuf1 = (unsigned short*)p; p += 64 * 512 * 2;
    unsigned short* xbf   = (unsigned short*)p; p += 64 * 512 * 2;
    unsigned short* hb[2] = {hbuf0, hbuf1};

    hipMemsetAsync(out, 0, sizeof(float), stream);

    setup_kernel<<<3984, 256, 0, stream>>>(enc_h, style, W_e2d_w, W_e2d_b,
                                           enc_out, attn_W, w_ih, w_hh,
                                           emb_table, dec_in,
                                           hbuf0, c, wcbf, encbf, ebf, M_bf);

    for (int t = 0; t < T; t++) {
        attn_step_kernel<<<64, 256, 0, stream>>>(hb[t & 1], M_bf, encbf, xbf);
        gates_step_kernel<<<128, 256, 0, stream>>>(xbf, hb[t & 1], hb[(t + 1) & 1],
                                                   ebf, wcbf, b_ih, b_hh,
                                                   c, hseqb, t);
    }

    proj_mfma_kernel<<<500, 256, 0, stream>>>(hseqb, proj_w, proj_b, partial);
    sumexp_reduce_kernel<<<42, 256, 0, stream>>>(partial, sumexp);
    loss_kernel<<<64, 64, 0, stream>>>(hseqb, proj_w, proj_b, sumexp, seq_label, out);
}

// Round 6
// 894.703 us; speedup vs baseline: 1.0502x; 1.0502x over previous
//
#include <hip/hip_runtime.h>
#include <hip/hip_bf16.h>
#include <math.h>

#define B 64
#define S 64
#define T 21
#define HID 512
#define VOCAB 32000

typedef __bf16 bf16x8 __attribute__((ext_vector_type(8)));
typedef float f32x4 __attribute__((ext_vector_type(4)));

union BF8 { unsigned short u[8]; bf16x8 v; uint4 q; };

__device__ __forceinline__ unsigned short f32_to_bf16_rne(float x) {
    union { float f; unsigned int u; } v;
    v.f = x;
    unsigned int u = v.u;
    unsigned int r = (u + 0x7FFFu + ((u >> 16) & 1u)) >> 16;
    return (unsigned short)r;
}

__device__ __forceinline__ float bf16_to_f32(unsigned short x) {
    union { unsigned int u; float f; } v;
    v.u = ((unsigned int)x) << 16;
    return v.f;
}

__device__ __forceinline__ bf16x8 cvt8(const float* p) {
    float4 f0 = *(const float4*)p;
    float4 f1 = *(const float4*)(p + 4);
    BF8 r;
    r.u[0] = f32_to_bf16_rne(f0.x); r.u[1] = f32_to_bf16_rne(f0.y);
    r.u[2] = f32_to_bf16_rne(f0.z); r.u[3] = f32_to_bf16_rne(f0.w);
    r.u[4] = f32_to_bf16_rne(f1.x); r.u[5] = f32_to_bf16_rne(f1.y);
    r.u[6] = f32_to_bf16_rne(f1.z); r.u[7] = f32_to_bf16_rne(f1.w);
    return r.v;
}

// Grid barrier: release arrive, RELAXED spin (no per-poll invalidation),
// one acquire at exit. Monotone counter, no reset.
__device__ __forceinline__ void gbar(unsigned* bar, unsigned target) {
    __syncthreads();
    if (threadIdx.x == 0) {
        __hip_atomic_fetch_add(bar, 1u, __ATOMIC_RELEASE, __HIP_MEMORY_SCOPE_AGENT);
        while (__hip_atomic_load(bar, __ATOMIC_RELAXED, __HIP_MEMORY_SCOPE_AGENT) < target)
            __builtin_amdgcn_s_sleep(2);
        (void)__hip_atomic_load(bar, __ATOMIC_ACQUIRE, __HIP_MEMORY_SCOPE_AGENT);
    }
    __syncthreads();
}

// ---------------------------------------------------------------------------
// Fused setup. Block ranges:
//  [0,64)       h0 -> hb0 bf16
//  [64,2112)    wc2: [w_ih[:, :512] | w_hh] -> bf16 [n][1024]
//  [2112,2624)  mgemm: M[bs][j] = enc_out . attn_W  (bf16)
//  [2624,3296)  gegemm: geT[t][n][b] = emb(dec_in) . w_ih[:,512:].T + b_ih + b_hh
// ---------------------------------------------------------------------------
__global__ __launch_bounds__(256) void setup_kernel(
        const float* __restrict__ enc_h, const float* __restrict__ style,
        const float* __restrict__ W_e2d, const float* __restrict__ W_e2d_b,
        const float* __restrict__ enc_out, const float* __restrict__ attn_W,
        const float* __restrict__ w_ih, const float* __restrict__ w_hh,
        const float* __restrict__ emb_table, const int* __restrict__ dec_in,
        const float* __restrict__ b_ih, const float* __restrict__ b_hh,
        unsigned short* __restrict__ hb0, unsigned short* __restrict__ wc2,
        unsigned short* __restrict__ M_bf, float* __restrict__ geT) {
    int bid = blockIdx.x;
    int tid = threadIdx.x;
    __shared__ __attribute__((aligned(16))) float smem[640];

    if (bid < 64) {
        int b = bid;
        for (int i = tid; i < 512; i += 256) smem[i] = enc_h[b * 512 + i];
        if (tid < 128) smem[512 + tid] = style[b * 512 + 384 + tid];
        __syncthreads();
        for (int j = tid; j < 512; j += 256) {
            const float4* w4 = (const float4*)(W_e2d + (size_t)j * 640);
            float acc = 0.f;
#pragma unroll 4
            for (int k4 = 0; k4 < 160; k4++) {
                float4 w = w4[k4];
                float4 iv = *(const float4*)(smem + k4 * 4);
                acc += w.x * iv.x + w.y * iv.y + w.z * iv.z + w.w * iv.w;
            }
            hb0[b * 512 + j] = f32_to_bf16_rne(acc + W_e2d_b[j]);
        }
    } else if (bid < 2112) {
        int n = bid - 64;
        for (int k = tid; k < 1024; k += 256) {
            float v = (k < 512) ? w_ih[(size_t)n * 1024 + k]
                                : w_hh[(size_t)n * 512 + (k - 512)];
            wc2[(size_t)n * 1024 + k] = f32_to_bf16_rne(v);
        }
    } else if (bid < 2624) {
        int idx = bid - 2112;
        int xm = idx & 63, y = idx >> 6;
        int w = tid >> 6, lane = tid & 63;
        int col = lane & 15, kq = lane >> 4;
        int m0 = xm * 64 + w * 16;

        bf16x8 af[16];
        const float* arow = enc_out + (size_t)(m0 + col) * 512 + kq * 8;
#pragma unroll
        for (int ks = 0; ks < 16; ks++) af[ks] = cvt8(arow + ks * 32);

#pragma unroll
        for (int nt = 0; nt < 4; nt++) {
            int j0 = y * 64 + nt * 16;
            const float* brow = attn_W + (size_t)(j0 + col) * 512 + kq * 8;
            f32x4 acc = {0.f, 0.f, 0.f, 0.f};
#pragma unroll
            for (int ks = 0; ks < 16; ks++) {
                bf16x8 bf = cvt8(brow + ks * 32);
                acc = __builtin_amdgcn_mfma_f32_16x16x32_bf16(af[ks], bf, acc, 0, 0, 0);
            }
#pragma unroll
            for (int reg = 0; reg < 4; reg++) {
                int m = m0 + kq * 4 + reg;
                M_bf[(size_t)m * 512 + j0 + col] = f32_to_bf16_rne(acc[reg]);
            }
        }
    } else {
        int idx = bid - 2624;
        int mi = idx / 32, ni = idx - mi * 32;   // 21 m-tiles x 32 n-tiles
        int w = tid >> 6, lane = tid & 63;
        int col = lane & 15, kq = lane >> 4;
        int m0 = mi * 64 + w * 16;

        bf16x8 af[16];
        {
            int bt = m0 + col;
            int tok = dec_in[bt];
            const float* arow = emb_table + (size_t)tok * 512 + kq * 8;
#pragma unroll
            for (int ks = 0; ks < 16; ks++) af[ks] = cvt8(arow + ks * 32);
        }
#pragma unroll
        for (int nt = 0; nt < 4; nt++) {
            int n0 = ni * 64 + nt * 16;
            const float* brow = w_ih + (size_t)(n0 + col) * 1024 + 512 + kq * 8;
            f32x4 acc = {0.f, 0.f, 0.f, 0.f};
#pragma unroll
            for (int ks = 0; ks < 16; ks++) {
                bf16x8 bf = cvt8(brow + ks * 32);
                acc = __builtin_amdgcn_mfma_f32_16x16x32_bf16(af[ks], bf, acc, 0, 0, 0);
            }
#pragma unroll
            for (int reg = 0; reg < 4; reg++) {
                int m = m0 + kq * 4 + reg;      // bt index
                int n = n0 + col;
                int bb = m / T, tt = m - bb * T;
                geT[((size_t)tt * 2048 + n) * 64 + bb] = acc[reg] + b_ih[n] + b_hh[n];
            }
        }
    }
}

// ---------------------------------------------------------------------------
// Persistent scan: grid(64) cooperative, block(256). Block b:
//  - owns batch b's attention (M[b] in swizzled LDS, staged once)
//  - owns gate rows {g*512 + b*8 + du} (W in swizzled LDS, staged once)
//  - c state for its 8 u x 64 b lives in registers across all 21 steps.
// Per step: phase1 attn (scores/softmax/ctx -> global) | barrier |
//           phase3 gates MFMA (K=1024: ctx|h) + geT + LSTM -> h | barrier.
// ---------------------------------------------------------------------------
__global__ __launch_bounds__(256) void scan_kernel(
        const unsigned short* __restrict__ M_bf,
        const float* __restrict__ enc_out,
        const unsigned short* __restrict__ wc2,
        const float* __restrict__ geT,
        unsigned short* __restrict__ hb0, unsigned short* __restrict__ hb1,
        unsigned short* __restrict__ ctxb, unsigned short* __restrict__ hseqb,
        unsigned* __restrict__ bar) {
    const int bk = blockIdx.x;
    const int tid = threadIdx.x;
    const int b = bk, u0 = bk * 8;
    const int lane = tid & 63, w = tid >> 6;
    const int col = lane & 15, kq = lane >> 4;

    __shared__ __attribute__((aligned(16))) unsigned short Mlds[64 * 512];
    __shared__ __attribute__((aligned(16))) unsigned short Wlds[32 * 1024];
    __shared__ __attribute__((aligned(16))) float fscr[2080];
    __shared__ float scp[4][64];
    __shared__ float sc[64];
    __shared__ float hls[512];

    // Stage M[b] (swizzled: chunk' = c ^ (row&7))
#pragma unroll
    for (int i = 0; i < 16; i++) {
        int idx = i * 256 + tid;
        int r = idx >> 6, c = idx & 63;
        *(uint4*)(Mlds + r * 512 + ((c ^ (r & 7)) * 8)) =
            *(const uint4*)(M_bf + ((size_t)(b * 64 + r)) * 512 + c * 8);
    }
    // Stage W rows (swizzled)
#pragma unroll
    for (int i = 0; i < 16; i++) {
        int idx = i * 256 + tid;
        int r = idx >> 7, c = idx & 127;
        int gr = (r >> 3) * 512 + u0 + (r & 7);
        *(uint4*)(Wlds + r * 1024 + ((c ^ (r & 7)) * 8)) =
            *(const uint4*)(wc2 + (size_t)gr * 1024 + c * 8);
    }

    float creg0 = 0.f, creg1 = 0.f;
    const int bb = tid & 63, duq = (tid >> 6) * 2;
    __syncthreads();

    unsigned target = 64;
    for (int t = 0; t < T; t++) {
        unsigned short* hcur = (t & 1) ? hb1 : hb0;
        unsigned short* hnxt = (t & 1) ? hb0 : hb1;

        // ---------------- phase 1: attention for batch b ----------------
        hls[tid] = bf16_to_f32(hcur[b * 512 + tid]);
        hls[tid + 256] = bf16_to_f32(hcur[b * 512 + tid + 256]);
        __syncthreads();
        {   // scores: s = lane, q = w covers d-range q*128..+128
            float acc = 0.f;
#pragma unroll
            for (int i = 0; i < 16; i++) {
                int c = w * 16 + i;
                BF8 mp;
                mp.q = *(const uint4*)(Mlds + lane * 512 + ((c ^ (lane & 7)) * 8));
                const float* hq = hls + w * 128 + i * 8;
#pragma unroll
                for (int j = 0; j < 8; j++) acc += bf16_to_f32(mp.u[j]) * hq[j];
            }
            scp[w][lane] = acc;
        }
        __syncthreads();
        if (tid < 64) {
            float v = scp[0][tid] + scp[1][tid] + scp[2][tid] + scp[3][tid];
            float m = v;
            for (int off = 32; off > 0; off >>= 1) m = fmaxf(m, __shfl_xor(m, off, 64));
            float e = __expf(v - m);
            float ss = e;
            for (int off = 32; off > 0; off >>= 1) ss += __shfl_xor(ss, off, 64);
            sc[tid] = e / ss;
        }
        __syncthreads();
        {   // ctx partials: w covers s-range, lane covers d = lane*8..+8
            float cp[8] = {0, 0, 0, 0, 0, 0, 0, 0};
#pragma unroll 4
            for (int si = 0; si < 16; si++) {
                int s = w * 16 + si;
                float a = sc[s];
                const float* ep = enc_out + ((size_t)(b * 64 + s)) * 512 + lane * 8;
                float4 e0 = *(const float4*)ep;
                float4 e1 = *(const float4*)(ep + 4);
                cp[0] += a * e0.x; cp[1] += a * e0.y; cp[2] += a * e0.z; cp[3] += a * e0.w;
                cp[4] += a * e1.x; cp[5] += a * e1.y; cp[6] += a * e1.z; cp[7] += a * e1.w;
            }
#pragma unroll
            for (int j = 0; j < 8; j++) fscr[w * 520 + lane * 8 + j] = cp[j];
        }
        __syncthreads();
        {   // reduce 4 partials, write ctx (bf16, packed u32 stores)
            int d = tid * 2;
            float v0 = fscr[d] + fscr[520 + d] + fscr[1040 + d] + fscr[1560 + d];
            float v1 = fscr[d + 1] + fscr[521 + d] + fscr[1041 + d] + fscr[1561 + d];
            unsigned pack = (unsigned)f32_to_bf16_rne(v0) |
                            ((unsigned)f32_to_bf16_rne(v1) << 16);
            *(unsigned*)(ctxb + b * 512 + d) = pack;
        }
        gbar(bar, target); target += 64;

        // ---------------- phase 3: gates + LSTM ----------------
        {
            int bA = w * 16 + col;
            const unsigned short* arow_c = ctxb + bA * 512 + kq * 8;
            const unsigned short* arow_h = hcur + bA * 512 + kq * 8;
            f32x4 acc0 = {0.f, 0.f, 0.f, 0.f};
            f32x4 acc1 = {0.f, 0.f, 0.f, 0.f};
            int sw0 = col & 7;
#pragma unroll
            for (int ks = 0; ks < 16; ks++) {
                bf16x8 af = *reinterpret_cast<const bf16x8*>(arow_c + ks * 32);
                int c = kq + 4 * ks;
                bf16x8 bf0 = *reinterpret_cast<const bf16x8*>(
                    Wlds + col * 1024 + ((c ^ sw0) * 8));
                bf16x8 bf1 = *reinterpret_cast<const bf16x8*>(
                    Wlds + (16 + col) * 1024 + ((c ^ sw0) * 8));
                acc0 = __builtin_amdgcn_mfma_f32_16x16x32_bf16(af, bf0, acc0, 0, 0, 0);
                acc1 = __builtin_amdgcn_mfma_f32_16x16x32_bf16(af, bf1, acc1, 0, 0, 0);
            }
#pragma unroll
            for (int ks = 16; ks < 32; ks++) {
                bf16x8 af = *reinterpret_cast<const bf16x8*>(arow_h + (ks - 16) * 32);
                int c = kq + 4 * ks;
                bf16x8 bf0 = *reinterpret_cast<const bf16x8*>(
                    Wlds + col * 1024 + ((c ^ sw0) * 8));
                bf16x8 bf1 = *reinterpret_cast<const bf16x8*>(
                    Wlds + (16 + col) * 1024 + ((c ^ sw0) * 8));
                acc0 = __builtin_amdgcn_mfma_f32_16x16x32_bf16(af, bf0, acc0, 0, 0, 0);
                acc1 = __builtin_amdgcn_mfma_f32_16x16x32_bf16(af, bf1, acc1, 0, 0, 0);
            }
            // D: row (kq*4+reg) = b-local, col = n-local. Scatter to fscr[n][b].
#pragma unroll
            for (int reg = 0; reg < 4; reg++) {
                fscr[col * 65 + w * 16 + kq * 4 + reg] = acc0[reg];
                fscr[(16 + col) * 65 + w * 16 + kq * 4 + reg] = acc1[reg];
            }
        }
        __syncthreads();
        {   // LSTM: thread (bb, du = duq..duq+1)
#pragma unroll
            for (int i = 0; i < 2; i++) {
                int du = duq + i;
                int u = u0 + du;
                const float* ge = geT + ((size_t)t * 2048) * 64;
                float g0 = fscr[(0 + du) * 65 + bb]  + ge[(size_t)(u) * 64 + bb];
                float g1 = fscr[(8 + du) * 65 + bb]  + ge[(size_t)(512 + u) * 64 + bb];
                float g2 = fscr[(16 + du) * 65 + bb] + ge[(size_t)(1024 + u) * 64 + bb];
                float g3 = fscr[(24 + du) * 65 + bb] + ge[(size_t)(1536 + u) * 64 + bb];
                float ig = 1.f / (1.f + __expf(-g0));
                float fg = 1.f / (1.f + __expf(-g1));
                float gt = tanhf(g2);
                float og = 1.f / (1.f + __expf(-g3));
                float& cr = i ? creg1 : creg0;
                cr = fg * cr + ig * gt;
                float hn = og * tanhf(cr);
                unsigned short hv = f32_to_bf16_rne(hn);
                hnxt[bb * 512 + u] = hv;
                hseqb[((size_t)bb * T + t) * 512 + u] = hv;
            }
        }
        gbar(bar, target); target += 64;
    }
}

// ---------------------------------------------------------------------------
// Projection + exp-sum. grid(500), block(256). Wave wv: nhalf = wv&1 (32 n as
// 2 tiles, A-frags hoisted + inline cvt), mhalf = wv>>1 (which 16 of the 32
// staged m rows). hseq tile in XOR-swizzled LDS; 1 ds_read feeds 2 MFMAs.
// Epilogue: 8 exps -> one LDS atomicAdd per lane per tile.
// ---------------------------------------------------------------------------
__global__ __launch_bounds__(256) void proj_mfma_kernel(
        const unsigned short* __restrict__ hseqb,
        const float* __restrict__ proj_w,
        const float* __restrict__ proj_b,
        float* __restrict__ partial) {
    int tid = threadIdx.x;
    int wv = tid >> 6, lane = tid & 63;
    int col = lane & 15, kq = lane >> 4;
    int nhalf = wv & 1, mhalf = wv >> 1;
    int n0 = blockIdx.x * 64 + nhalf * 32;

    bf16x8 Af0[16], Af1[16];
    {
        const float* w0 = proj_w + (size_t)(n0 + col) * 512 + kq * 8;
        const float* w1 = proj_w + (size_t)(n0 + 16 + col) * 512 + kq * 8;
#pragma unroll
        for (int ks = 0; ks < 16; ks++) {
            Af0[ks] = cvt8(w0 + ks * 32);
            Af1[ks] = cvt8(w1 + ks * 32);
        }
    }
    float4 bias0 = *(const float4*)(proj_b + n0 + kq * 4);
    float4 bias1 = *(const float4*)(proj_b + n0 + 16 + kq * 4);

    __shared__ __attribute__((aligned(16))) unsigned short alds[32 * 512];
    __shared__ float esum[1344];
    for (int i = tid; i < 1344; i += 256) esum[i] = 0.f;
    __syncthreads();

    for (int mt = 0; mt < 42; mt++) {
        int mA = mt * 32;
        __syncthreads();
#pragma unroll
        for (int i = 0; i < 8; i++) {
            int idx = i * 256 + tid;
            int r = idx >> 6, c = idx & 63;
            *(uint4*)(alds + r * 512 + ((c ^ (r & 7)) * 8)) =
                *(const uint4*)(hseqb + (size_t)(mA + r) * 512 + c * 8);
        }
        __syncthreads();
        int rr = mhalf * 16 + col;
        int sw = rr & 7;
        f32x4 acc0 = {0.f, 0.f, 0.f, 0.f};
        f32x4 acc1 = {0.f, 0.f, 0.f, 0.f};
#pragma unroll
        for (int ks = 0; ks < 16; ks++) {
            int c = kq + 4 * ks;
            bf16x8 bf = *reinterpret_cast<const bf16x8*>(
                alds + rr * 512 + ((c ^ sw) * 8));
            acc0 = __builtin_amdgcn_mfma_f32_16x16x32_bf16(Af0[ks], bf, acc0, 0, 0, 0);
            acc1 = __builtin_amdgcn_mfma_f32_16x16x32_bf16(Af1[ks], bf, acc1, 0, 0, 0);
        }
        float e = __expf(acc0[0] + bias0.x) + __expf(acc0[1] + bias0.y) +
                  __expf(acc0[2] + bias0.z) + __expf(acc0[3] + bias0.w) +
                  __expf(acc1[0] + bias1.x) + __expf(acc1[1] + bias1.y) +
                  __expf(acc1[2] + bias1.z) + __expf(acc1[3] + bias1.w);
        atomicAdd(&esum[mA + rr], e);
    }
    __syncthreads();
    for (int i = tid; i < 1344; i += 256)
        partial[(size_t)blockIdx.x * 1344 + i] = esum[i];
}

// ---------------------------------------------------------------------------
__global__ __launch_bounds__(256) void sumexp_reduce_kernel(
        const float* __restrict__ partial, float* __restrict__ sumexp) {
    int m = blockIdx.x * 32 + (threadIdx.x >> 3);
    int sub = threadIdx.x & 7;
    float s = 0.f;
    for (int nb = sub; nb < 500; nb += 8) s += partial[(size_t)nb * 1344 + m];
    s += __shfl_xor(s, 1, 64);
    s += __shfl_xor(s, 2, 64);
    s += __shfl_xor(s, 4, 64);
    if (sub == 0) sumexp[m] = s;
}

// ---------------------------------------------------------------------------
__global__ __launch_bounds__(64) void loss_kernel(
        const unsigned short* __restrict__ hseqb,
        const float* __restrict__ proj_w, const float* __restrict__ proj_b,
        const float* __restrict__ sumexp, const int* __restrict__ seq_label,
        float* __restrict__ out) {
    int b = blockIdx.x;
    int lane = threadIdx.x;
    float num = 0.f, den = 0.f;
    for (int t = 0; t < T; t++) {
        int label = seq_label[b * T + t];
        const unsigned short* hp = hseqb + ((size_t)b * T + t) * 512;
        const float* wp = proj_w + (size_t)label * 512;
        float acc = 0.f;
#pragma unroll
        for (int i = 0; i < 8; i++)
            acc += bf16_to_f32(hp[lane + 64 * i]) * wp[lane + 64 * i];
        for (int off = 32; off > 0; off >>= 1) acc += __shfl_xor(acc, off, 64);
        if (lane == 0) {
            float nll = logf(sumexp[b * T + t]) - (acc + proj_b[label]);
            float mask = (label > 0) ? 1.f : 0.f;
            num += mask * nll;
            den += mask;
        }
    }
    if (lane == 0) atomicAdd(out, (num / (den + 1e-6f)) * (1.f / 64.f));
}

// ---------------------------------------------------------------------------
extern "C" void kernel_launch(void* const* d_in, const int* in_sizes, int n_in,
                              void* d_out, int out_size, void* d_ws, size_t ws_size,
                              hipStream_t stream) {
    const float* enc_h     = (const float*)d_in[0];
    const float* enc_out   = (const float*)d_in[1];
    const int*   seq_label = (const int*)d_in[3];
    const int*   dec_in    = (const int*)d_in[4];
    const float* style     = (const float*)d_in[5];
    const float* W_e2d_w   = (const float*)d_in[6];
    const float* W_e2d_b   = (const float*)d_in[7];
    const float* attn_W    = (const float*)d_in[8];
    const float* emb_table = (const float*)d_in[9];
    const float* w_ih      = (const float*)d_in[10];
    const float* w_hh      = (const float*)d_in[11];
    const float* b_ih      = (const float*)d_in[12];
    const float* b_hh      = (const float*)d_in[13];
    const float* proj_w    = (const float*)d_in[14];
    const float* proj_b    = (const float*)d_in[15];
    float* out = (float*)d_out;

    char* p = (char*)d_ws;
    float* partial = (float*)p;                    p += 500 * 1344 * 4;
    float* sumexp  = (float*)p;                    p += 1344 * 4 + 64;
    float* geT     = (float*)p;                    p += (size_t)21 * 2048 * 64 * 4;
    unsigned short* M_bf  = (unsigned short*)p;    p += (size_t)4096 * 512 * 2;
    unsigned short* wc2   = (unsigned short*)p;    p += (size_t)2048 * 1024 * 2;
    unsigned short* hseqb = (unsigned short*)p;    p += (size_t)1344 * 512 * 2;
    unsigned short* hb0   = (unsigned short*)p;    p += 64 * 512 * 2;
    unsigned short* hb1   = (unsigned short*)p;    p += 64 * 512 * 2;
    unsigned short* ctxb  = (unsigned short*)p;    p += 64 * 512 * 2;
    unsigned* bar = (unsigned*)p;                  p += 256;

    hipMemsetAsync(out, 0, sizeof(float), stream);
    hipMemsetAsync(bar, 0, 256, stream);

    setup_kernel<<<3296, 256, 0, stream>>>(enc_h, style, W_e2d_w, W_e2d_b,
                                           enc_out, attn_W, w_ih, w_hh,
                                           emb_table, dec_in, b_ih, b_hh,
                                           hb0, wc2, M_bf, geT);

    {
        void* args[] = {(void*)&M_bf, (void*)&enc_out, (void*)&wc2, (void*)&geT,
                        (void*)&hb0, (void*)&hb1, (void*)&ctxb, (void*)&hseqb,
                        (void*)&bar};
        hipLaunchCooperativeKernel((const void*)scan_kernel, dim3(64),
                                   dim3(256), args, 0, stream);
    }

    proj_mfma_kernel<<<500, 256, 0, stream>>>(hseqb, proj_w, proj_b, partial);
    sumexp_reduce_kernel<<<42, 256, 0, stream>>>(partial, sumexp);
    loss_kernel<<<64, 64, 0, stream>>>(hseqb, proj_w, proj_b, sumexp, seq_label, out);
}